// Round 11
// baseline (217.726 us; speedup 1.0000x reference)
//
#include <hip/hip_runtime.h>
#include <hip/hip_bf16.h>

#define BB 1024
#define LL 2048
#define KK 8192

typedef _Float16 f16x8 __attribute__((ext_vector_type(8)));
typedef _Float16 f16x4 __attribute__((ext_vector_type(4)));
typedef _Float16 f16x2 __attribute__((ext_vector_type(2)));
typedef float    f32x4 __attribute__((ext_vector_type(4)));

__device__ __forceinline__ float leakyf(float v){ return fmaxf(v, 0.001f*v); }
__device__ __forceinline__ f16x2 pkrtz(float a, float b){
    return __builtin_bit_cast(f16x2, __builtin_amdgcn_cvt_pkrtz(a, b));
}
// MFMA with the B operand (weights) pinned to AGPRs — frees arch VGPRs (no spills).
// NOTE: verbatim R7 form ("=v") — R7's emitted schedule is hardware-validated; do not
// perturb (inline-asm MFMA hazards are not modeled by the compiler; R8-R10 reshuffles NaN'd).
__device__ __forceinline__ f32x4 mfma_w(f16x8 a, f16x8 w_agpr, f32x4 c){
    f32x4 d;
    asm("v_mfma_f32_16x16x32_f16 %0, %1, %2, %3"
        : "=v"(d) : "v"(a), "a"(w_agpr), "v"(c));
    return d;
}

// ---------------- encoder: fused conv1x1 (3->64->128->64) + global max over L ----------------
// VERBATIM R7 (passed @119us). One block per b, 4 waves; W2/W3 in AGPRs; DPP+perm packed
// dword LDS stores; quad-XOR swizzle; b128 reads; same-iteration RAW only.
__global__ __launch_bounds__(256, 2) void encoder_mfma(
    const float* __restrict__ x,
    const float* __restrict__ W1, const float* __restrict__ b1,
    const float* __restrict__ W2, const float* __restrict__ b2,
    const float* __restrict__ W3, const float* __restrict__ b3,
    float* __restrict__ z_out, _Float16* __restrict__ zh_out)
{
    const int b    = blockIdx.x;
    const int t    = threadIdx.x;
    const int wave = t >> 6;
    const int lane = t & 63;
    const int col  = lane & 15;
    const int quad = lane >> 4;

    __shared__ __align__(16) unsigned h2l[4*1088];  // per-wave 1088 dw = 16 rows x 68 dw
    __shared__ float red[4][64];
    _Float16* h2h = (_Float16*)h2l;

    // B-frags layer 2 (AGPR-resident): B[k=c][n=o2], o2 = nt*16+col, c = quad*8+32ks+j
    f16x8 w2f[2][8];
    #pragma unroll
    for (int ks=0; ks<2; ks++){
        #pragma unroll
        for (int nt=0; nt<8; nt++){
            const float* p = W2 + (nt*16+col)*64 + quad*8 + 32*ks;
            f16x8 f;
            #pragma unroll
            for (int j=0;j<8;j++) f[j] = (_Float16)p[j];
            w2f[ks][nt] = f;
        }
    }
    // B-frags layer 3 (AGPR-resident): B[k=o2][n=o3]
    f16x8 w3f[4][4];
    #pragma unroll
    for (int ks=0; ks<4; ks++){
        #pragma unroll
        for (int nt=0; nt<4; nt++){
            const float* p = W3 + (nt*16+col)*128 + quad*8 + 32*ks;
            f16x8 f;
            #pragma unroll
            for (int j=0;j<8;j++) f[j] = (_Float16)p[j];
            w3f[ks][nt] = f;
        }
    }
    // layer-1 weights packed per-lane (channels quad*8 + 2*j2{+1} + 32ks)
    f16x2 w1p[2][4][3];
    f16x2 b1p[2][4];
    #pragma unroll
    for (int ks=0; ks<2; ks++){
        #pragma unroll
        for (int j2=0; j2<4; j2++){
            int c0 = quad*8 + 2*j2 + 32*ks;
            #pragma unroll
            for (int i=0;i<3;i++){
                f16x2 w; w[0] = (_Float16)W1[c0*3+i]; w[1] = (_Float16)W1[(c0+1)*3+i];
                w1p[ks][j2][i] = w;
            }
            f16x2 bb; bb[0] = (_Float16)b1[c0]; bb[1] = (_Float16)b1[c0+1];
            b1p[ks][j2] = bb;
        }
    }
    // b2 as packed pairs (same channel both halves; pair = two position-rows)
    f16x2 b2p[8];
    #pragma unroll
    for (int nt=0; nt<8; nt++){
        _Float16 bv = (_Float16)b2[nt*16+col];
        f16x2 p; p[0]=bv; p[1]=bv; b2p[nt]=p;
    }

    f16x2 k001; k001[0] = (_Float16)0.001f; k001[1] = (_Float16)0.001f;
    f32x4 zc; zc[0]=0.f; zc[1]=0.f; zc[2]=0.f; zc[3]=0.f;

    f32x4 hm[4];
    #pragma unroll
    for (int nt=0;nt<4;nt++){
        hm[nt][0] = -__builtin_inff(); hm[nt][1] = -__builtin_inff();
        hm[nt][2] = -__builtin_inff(); hm[nt][3] = -__builtin_inff();
    }

    const float* xb = x + (size_t)b*3*LL;
    const int pbase = wave*16 + col;
    const int rswz  = (col >> 2) << 4;       // read-side row-quad XOR (halves domain)
    // write base (dwords): row = quad*4 + (col&1); dword col = col>>1 (+ (nt^quad)*8 in loop)
    const int wbase_dw = wave*1088 + (quad*4 + (col&1))*68 + (col>>1);
    // perm selector: even lane -> {P.lo, Q.lo} (pos r), odd -> {Q.hi, P.hi} (pos r+1)
    const unsigned selA = (col & 1) ? 0x03020706u : 0x05040100u;

    float x0n = xb[pbase], x1n = xb[LL+pbase], x2n = xb[2*LL+pbase];

    #pragma unroll 1
    for (int it=0; it<LL/64; it++){
        const float x0 = x0n, x1 = x1n, x2 = x2n;
        {   // prefetch next iter's x
            int itn = it+1 < 32 ? it+1 : 31;
            int pn = itn*64 + pbase;
            x0n = xb[pn]; x1n = xb[LL+pn]; x2n = xb[2*LL+pn];
        }
        f16x2 xh0; xh0[0] = (_Float16)x0; xh0[1] = xh0[0];
        f16x2 xh1; xh1[0] = (_Float16)x1; xh1[1] = xh1[0];
        f16x2 xh2; xh2[0] = (_Float16)x2; xh2[1] = xh2[0];

        // layer 1 -> A-frags (packed leaky)
        f16x8 a2[2];
        #pragma unroll
        for (int ks=0; ks<2; ks++){
            f16x8 a;
            #pragma unroll
            for (int j2=0; j2<4; j2++){
                f16x2 v = b1p[ks][j2];
                v += w1p[ks][j2][0]*xh0;
                v += w1p[ks][j2][1]*xh1;
                v += w1p[ks][j2][2]*xh2;
                v = __builtin_elementwise_max(v, v*k001);
                a[2*j2]   = v[0];
                a[2*j2+1] = v[1];
            }
            a2[ks] = a;
        }

        // layer 2: AGPR-weight MFMAs; epilogue packs (2pos x 1ch) -> (1pos x 2ch) dwords
        // via DPP xor-1 + v_perm, then one ds_write2_b32 per nt.
        #pragma unroll
        for (int nt=0; nt<8; nt++){
            f32x4 acc = mfma_w(a2[0], w2f[0][nt], zc);
            acc = mfma_w(a2[1], w2f[1][nt], acc);
            f16x2 p01 = pkrtz(acc[0], acc[1]);   // pos r, r+1   (r = quad*4)
            f16x2 p23 = pkrtz(acc[2], acc[3]);   // pos r+2, r+3
            p01 += b2p[nt];  p23 += b2p[nt];
            p01 = __builtin_elementwise_max(p01, p01*k001);
            p23 = __builtin_elementwise_max(p23, p23*k001);
            unsigned P01 = __builtin_bit_cast(unsigned, p01);
            unsigned P23 = __builtin_bit_cast(unsigned, p23);
            unsigned Q01 = (unsigned)__builtin_amdgcn_mov_dpp((int)P01, 0xB1, 0xF, 0xF, true);
            unsigned Q23 = (unsigned)__builtin_amdgcn_mov_dpp((int)P23, 0xB1, 0xF, 0xF, true);
            unsigned d0 = __builtin_amdgcn_perm(Q01, P01, selA);   // (pos r+(c&1),   ch pair)
            unsigned d1 = __builtin_amdgcn_perm(Q23, P23, selA);   // (pos r+2+(c&1), ch pair)
            unsigned* wp = &h2l[wbase_dw + ((nt ^ quad)<<3)];
            wp[0]   = d0;
            wp[136] = d1;
        }

        // layer 3: swizzled b128 reads, AGPR-weight MFMAs
        const int roff = wave*2176 + col*136;
        f16x8 a30 = *(const f16x8*)&h2h[roff + (( 0 + quad*8) ^ rswz)];
        f16x8 a31 = *(const f16x8*)&h2h[roff + ((32 + quad*8) ^ rswz)];
        f16x8 a32 = *(const f16x8*)&h2h[roff + ((64 + quad*8) ^ rswz)];
        f16x8 a33 = *(const f16x8*)&h2h[roff + ((96 + quad*8) ^ rswz)];
        #pragma unroll
        for (int nt=0; nt<4; nt++){
            f32x4 acc = mfma_w(a30, w3f[0][nt], zc);
            acc = mfma_w(a31, w3f[1][nt], acc);
            acc = mfma_w(a32, w3f[2][nt], acc);
            acc = mfma_w(a33, w3f[3][nt], acc);
            hm[nt][0] = fmaxf(hm[nt][0], acc[0]);
            hm[nt][1] = fmaxf(hm[nt][1], acc[1]);
            hm[nt][2] = fmaxf(hm[nt][2], acc[2]);
            hm[nt][3] = fmaxf(hm[nt][3], acc[3]);
        }
    }

    #pragma unroll
    for (int nt=0; nt<4; nt++){
        float v = fmaxf(fmaxf(hm[nt][0], hm[nt][1]), fmaxf(hm[nt][2], hm[nt][3]));
        v = fmaxf(v, __shfl_xor(v, 16, 64));
        v = fmaxf(v, __shfl_xor(v, 32, 64));
        if (quad == 0) red[wave][nt*16 + col] = v;
    }
    __syncthreads();
    if (t < 64){
        float v = fmaxf(fmaxf(red[0][t], red[1][t]), fmaxf(red[2][t], red[3][t])) + b3[t];
        z_out[(size_t)b*64 + t] = v;
        zh_out[(size_t)b*64 + t] = (_Float16)v;
    }
}

// ---------------- VQ: fused codebook-slice prep (fp16 + ||c||^2 in LDS) + argmin GEMM -------
// VERBATIM R6 (passed). grid 512: rb = bid>>5 (16 row-blocks of 64), ns = bid&31 (32 slices).
__global__ __launch_bounds__(256, 2) void vq_mfma(
    const _Float16* __restrict__ zh, const float* __restrict__ cb,
    float* __restrict__ pval, int* __restrict__ pidx)
{
    const int t    = threadIdx.x;
    const int wave = t >> 6;
    const int lane = t & 63;
    const int col  = lane & 15;
    const int quad = lane >> 4;
    const int rb   = blockIdx.x >> 5;
    const int ns   = blockIdx.x & 31;

    __shared__ __align__(16) _Float16 cbl[256*72];   // 72-half stride: conflict-free b128 reads
    __shared__ float cnl[256];

    // stage this block's 256-entry slice: fp32 -> fp16 LDS + ||c||^2
    const int eoff = wave*4 + (lane >> 4);
    const int sub  = lane & 15;
    #pragma unroll 4
    for (int p=0; p<16; p++){
        const int el = p*16 + eoff;
        const float4 v = *(const float4*)(cb + ((size_t)(ns*256 + el))*64 + sub*4);
        f16x2 h0 = pkrtz(v.x, v.y);
        f16x2 h1 = pkrtz(v.z, v.w);
        f16x4 hv; hv[0]=h0[0]; hv[1]=h0[1]; hv[2]=h1[0]; hv[3]=h1[1];
        *(f16x4*)(cbl + el*72 + sub*4) = hv;
        float d = v.x*v.x + v.y*v.y + v.z*v.z + v.w*v.w;
        #pragma unroll
        for (int s=1; s<16; s<<=1) d += __shfl_xor(d, s, 64);
        if (sub == 0) cnl[el] = d;
    }
    __syncthreads();

    const int rowbase = rb*64 + wave*16;
    f16x8 az[2];
    az[0] = *(const f16x8*)&zh[(size_t)(rowbase+col)*64 + quad*8];
    az[1] = *(const f16x8*)&zh[(size_t)(rowbase+col)*64 + quad*8 + 32];

    f32x4 zc; zc[0]=0.f; zc[1]=0.f; zc[2]=0.f; zc[3]=0.f;
    float best[4] = {__builtin_inff(),__builtin_inff(),__builtin_inff(),__builtin_inff()};
    int   bidx[4] = {0,0,0,0};

    #pragma unroll 4
    for (int nt=0; nt<16; nt++){
        const int el = nt*16 + col;
        f16x8 c0 = *(const f16x8*)&cbl[el*72 + quad*8];
        f16x8 c1 = *(const f16x8*)&cbl[el*72 + quad*8 + 32];
        float cnc = cnl[el];
        f32x4 acc = __builtin_amdgcn_mfma_f32_16x16x32_f16(az[0], c0, zc, 0,0,0);
        acc = __builtin_amdgcn_mfma_f32_16x16x32_f16(az[1], c1, acc, 0,0,0);
        const int myidx = ns*256 + el;
        #pragma unroll
        for (int r=0; r<4; r++){
            float d = fmaf(-2.0f, acc[r], cnc);
            if (d < best[r]){ best[r] = d; bidx[r] = myidx; }
        }
    }

    #pragma unroll
    for (int r=0; r<4; r++){
        float v = best[r]; int i = bidx[r];
        #pragma unroll
        for (int s=1; s<16; s<<=1){
            float ov = __shfl_xor(v, s, 64);
            int   oi = __shfl_xor(i, s, 64);
            if (ov < v || (ov == v && oi < i)){ v = ov; i = oi; }
        }
        if (col == 0){
            int row = rowbase + quad*4 + r;
            pval[row*32 + ns] = v;
            pidx[row*32 + ns] = i;
        }
    }
}

// ---------------- decoder (argmin-merge + 64->128->64->3) + atomic loss ----------------
__global__ __launch_bounds__(128, 2) void decoder_kernel(
    const float* __restrict__ z,
    const float* __restrict__ pval, const int* __restrict__ pidx,
    const float* __restrict__ cb,
    const float* __restrict__ U1, const float* __restrict__ c1,
    const float* __restrict__ U2, const float* __restrict__ c2,
    const float* __restrict__ U3, const float* __restrict__ c3,
    float* __restrict__ xrec, float* __restrict__ loss)
{
    const int b = blockIdx.x;
    const int t = threadIdx.x;
    __shared__ int kk_s;
    __shared__ float zst[64];
    __shared__ float g1[128];
    __shared__ float g2[64];
    if (t < 32){
        float v = pval[b*32 + t]; int i = pidx[b*32 + t];
        #pragma unroll
        for (int s=1; s<32; s<<=1){
            float ov = __shfl_xor(v, s, 32);
            int   oi = __shfl_xor(i, s, 32);
            if (ov < v || (ov == v && oi < i)){ v = ov; i = oi; }
        }
        if (t==0) kk_s = i;
    }
    __syncthreads();
    const int kk = kk_s;
    if (t < 64){
        float zv = z[(size_t)b*64 + t];
        float zq = cb[(size_t)kk*64 + t];
        float diff = zq - zv;
        zst[t] = zv + diff;                 // straight-through forward value
        float p = diff*diff;
        #pragma unroll
        for (int s=32;s>0;s>>=1) p += __shfl_xor(p, s, 64);
        if (t==0) atomicAdd(loss, p * (1.25f / 65536.0f));   // loss zero-initialized by memset
    }
    __syncthreads();
    {
        float v = c1[t];
        #pragma unroll
        for (int d=0; d<64; d++) v = fmaf(zst[d], U1[d*128+t], v);
        g1[t] = leakyf(v);
    }
    __syncthreads();
    if (t < 64){
        float v = c2[t];
        #pragma unroll
        for (int j=0;j<128;j++) v = fmaf(g1[j], U2[j*64+t], v);
        g2[t] = leakyf(v);
    }
    __syncthreads();
    if (t < 3){
        float v = c3[t];
        #pragma unroll
        for (int j=0;j<64;j++) v = fmaf(g2[j], U3[j*3+t], v);
        xrec[(size_t)b*3 + t] = v;
    }
}

extern "C" void kernel_launch(void* const* d_in, const int* in_sizes, int n_in,
                              void* d_out, int out_size, void* d_ws, size_t ws_size,
                              hipStream_t stream)
{
    const float* x  = (const float*)d_in[0];
    const float* W1 = (const float*)d_in[1];
    const float* b1 = (const float*)d_in[2];
    const float* W2 = (const float*)d_in[3];
    const float* b2 = (const float*)d_in[4];
    const float* W3 = (const float*)d_in[5];
    const float* b3 = (const float*)d_in[6];
    const float* cb = (const float*)d_in[7];
    const float* U1 = (const float*)d_in[8];
    const float* c1 = (const float*)d_in[9];
    const float* U2 = (const float*)d_in[10];
    const float* c2 = (const float*)d_in[11];
    const float* U3 = (const float*)d_in[12];
    const float* c3 = (const float*)d_in[13];

    float* out  = (float*)d_out;
    float* xrec = out;              // [1024*3]
    float* loss = out + 3072;       // [1]
    float* z    = out + 3073;       // [1024*64]

    char* ws = (char*)d_ws;
    _Float16* zh    = (_Float16*)ws;                    // 128 KB
    float*    pval  = (float*)(ws + 131072);            // 128 KB
    int*      pidx  = (int*)(ws + 262144);              // 128 KB

    hipMemsetAsync(loss, 0, sizeof(float), stream);     // zero the atomic loss accumulator
    hipLaunchKernelGGL(encoder_mfma, dim3(BB), dim3(256), 0, stream,
                       x, W1, b1, W2, b2, W3, b3, z, zh);
    hipLaunchKernelGGL(vq_mfma, dim3(512), dim3(256), 0, stream, zh, cb, pval, pidx);
    hipLaunchKernelGGL(decoder_kernel, dim3(BB), dim3(128), 0, stream,
                       z, pval, pidx, cb, U1, c1, U2, c2, U3, c3, xrec, loss);
}